// Round 7
// baseline (211.515 us; speedup 1.0000x reference)
//
#include <hip/hip_runtime.h>
#include <math.h>

// Problem constants (from reference)
#define NPATCH 8192
#define KC     10
#define DIN    1024
#define DH     512
#define DA     256
#define NCLS   4

typedef unsigned short u16;
typedef short bf16x8 __attribute__((ext_vector_type(8)));   // 8 bf16 = 4 VGPRs
typedef float f32x4  __attribute__((ext_vector_type(4)));

// Workspace layout (bytes)
#define OFF_CNT   0                  // int[KC]
#define OFF_BAR   48                 // int[3] spin barriers (covered by 64B memset)
#define OFF_IDX   64                 // int[KC*NPATCH]
#define OFF_PSUM  327744             // float[KC*DH]
#define OFF_H     348224             // float[KC*DH]
#define OFF_H2    368768             // float[DA]
#define OFF_SRED  369792             // float[64*16]
#define OFF_W1P   373888             // u16[KC*32 panels][512][32] (granule-XOR packed)
#define OFF_W2P   10859648           // u16[KC*16 panels][512][32]
#define OFF_XC    16102528           // u16[8192][1024] compact bf16 x
#define OFF_H1    32879744           // u16[8192][512] compact bf16 h1
// total ~41.3 MB

__device__ __forceinline__ u16 f2bf(float f) {
  union { float f; unsigned u; } v; v.f = f;
  unsigned r = (v.u + 0x7fffu + ((v.u >> 16) & 1u)) >> 16;  // RNE
  return (u16)r;
}

struct __align__(8) U16x4 { u16 x, y, z, w; };

// Async global->LDS DMA, 16B/lane; LDS dest = wave-uniform base + lane*16,
// global SOURCE is per-lane (enables source-side swizzle).
__device__ __forceinline__ void dma16(const u16* gp, u16* lp) {
  __builtin_amdgcn_global_load_lds(
      (const __attribute__((address_space(1))) void*)gp,
      (__attribute__((address_space(3))) void*)lp, 16, 0, 0);
}

#define W1_TILES (KC * (DIN / 32) * (DH / 32))  // 5120
#define W2_TILES (KC * (DH / 32) * (DH / 32))   // 2560
#define NB_BUCKET 32
#define WT_PER_BLK 4
#define NB_PREP (NB_BUCKET + (W1_TILES + W2_TILES) / WT_PER_BLK)  // 1952

// Fused prep: bucket + zero psum (blocks 0..31); pack W1/W2 -> bf16 MFMA-B
// panels [panel][col][ki] with granule XOR swizzle: value(ki) stored at
// ki ^ (((col>>1)&3)<<3) so linear DMA staging yields 2-way-max LDS reads.
__global__ __launch_bounds__(256) void prep_kernel(
    const int* __restrict__ cid, int* __restrict__ cnt,
    int* __restrict__ idxlist, const float* __restrict__ W1,
    const float* __restrict__ W2, u16* __restrict__ W1p,
    u16* __restrict__ W2p, float* __restrict__ psum) {
  int b = blockIdx.x, t = threadIdx.x;
  if (b < NB_BUCKET) {
    int g = b * 256 + t;
    if (g < KC * DH) psum[g] = 0.f;
    __shared__ int lcnt[KC], lbase[KC];
    if (t < KC) lcnt[t] = 0;
    __syncthreads();
    int n = b * 256 + t;                 // NPATCH == 32*256
    int k = cid[n];
    int myoff = atomicAdd(&lcnt[k], 1);
    __syncthreads();
    if (t < KC) lbase[t] = atomicAdd(&cnt[t], lcnt[t]);
    __syncthreads();
    idxlist[k * NPATCH + lbase[k] + myoff] = n;
  } else {
    __shared__ u16 tile[32][33];
#pragma unroll
    for (int it = 0; it < WT_PER_BLK; ++it) {
      int bb = (b - NB_BUCKET) * WT_PER_BLK + it;
      const float* src;
      u16* dst;
      if (bb < W1_TILES) {
        int k = bb / 512, rem = bb % 512;
        int kb = rem / 16, n0 = (rem % 16) * 32;
        src = W1 + (size_t)k * DIN * DH + (size_t)kb * 32 * DH + n0;
        dst = W1p + (((size_t)(k * 32 + kb) * 512 + n0) * 32);
      } else {
        int b2 = bb - W1_TILES;
        int k = b2 / 256, rem = b2 % 256;
        int kb = rem / 16, n0 = (rem % 16) * 32;
        src = W2 + (size_t)k * DH * DH + (size_t)kb * 32 * DH + n0;
        dst = W2p + (((size_t)(k * 16 + kb) * 512 + n0) * 32);
      }
      {
        int ki = t >> 3, n4 = (t & 7) * 4;
        float4 v = *(const float4*)&src[(size_t)ki * DH + n4];
        tile[ki][n4 + 0] = f2bf(v.x);
        tile[ki][n4 + 1] = f2bf(v.y);
        tile[ki][n4 + 2] = f2bf(v.z);
        tile[ki][n4 + 3] = f2bf(v.w);
      }
      __syncthreads();
      {
        int n = t >> 3, ki = (t & 7) * 4;
        U16x4 o = {tile[ki + 0][n], tile[ki + 1][n], tile[ki + 2][n],
                   tile[ki + 3][n]};
        int kis = ki ^ (((n >> 1) & 3) << 3);   // granule XOR swizzle
        *(U16x4*)&dst[(size_t)n * 32 + kis] = o;
      }
      __syncthreads();
    }
  }
}

// Pack x into compact bucket-ordered bf16 xc[8192][1024].
// 256 blocks x 256 thr: block owns 32 compact rows; thread t: row t>>3,
// 128-elem span (t&7)*128.
__global__ __launch_bounds__(256) void pack_kernel(
    const float* __restrict__ x, const int* __restrict__ cnt,
    const int* __restrict__ idxlist, u16* __restrict__ xc) {
  const int b = blockIdx.x, t = threadIdx.x;
  int cb[KC];
  {
    int a = 0;
#pragma unroll
    for (int i = 0; i < KC; ++i) { cb[i] = a; a += cnt[i]; }
  }
  int row = b * 32 + (t >> 3);
  int k = 0;
#pragma unroll
  for (int i = 1; i < KC; ++i) k = (row >= cb[i]) ? i : k;
  int src = idxlist[k * NPATCH + (row - cb[k])];
  const float4* xp = (const float4*)(x + (size_t)src * DIN + (t & 7) * 128);
  U16x4* dst = (U16x4*)(xc + (size_t)row * DIN + (t & 7) * 128);
#pragma unroll
  for (int j = 0; j < 32; ++j) {
    float4 v = xp[j];
    U16x4 o = {f2bf(v.x), f2bf(v.y), f2bf(v.z), f2bf(v.w)};
    dst[j] = o;
  }
}

// m97-style GEMM tile: 128 rows x 128 cols, BK=32, 256 thr (4 waves,
// acc[4][4] per wave covering 64x64). A and B staged via global_load_lds
// (width 16) double-buffered; 2 barriers + counted vmcnt(4) per K-tile.
// A source-granule-swizzled (xc/h1 linear); B pre-swizzled in W?p.
// grid (4 slices, 10 k, 64 chunks): id = slice+4k+40*chunk; chunk stride
// 40%8==0 -> same-XCD panel reuse across chunks.

__global__ __launch_bounds__(256, 2) void phi1_kernel(
    const u16* __restrict__ xc, const u16* __restrict__ W1p,
    const float* __restrict__ b1, const int* __restrict__ cnt,
    u16* __restrict__ h1) {
  const int slice = blockIdx.x, k = blockIdx.y, chunk = blockIdx.z;
  const int cntk = cnt[k];
  const int row0 = chunk * 128;
  if (row0 >= cntk) return;
  int cbase = 0;
#pragma unroll
  for (int i = 0; i < KC - 1; ++i) cbase += (i < k) ? cnt[i] : 0;

  const int tid = threadIdx.x;
  const int w = tid >> 6, lane = tid & 63;
  const int quad = lane >> 4, l16 = lane & 15;
  const int wr = w >> 1, wc = w & 1;
  const int rl = lane >> 2, gl = lane & 3;   // staging row-in-group / granule

  __shared__ __align__(16) u16 lds[17408];   // As 2x8KB | Bs 2x8KB; H reuse
  u16* As = lds;
  u16* Bs = lds + 8192;

  const size_t arow0 = (size_t)(cbase + row0);

  // prologue: stage K-tile 0 into buf 0 (4 DMA issues per wave)
#pragma unroll
  for (int jj = 0; jj < 2; ++jj) {
    int rg = w * 2 + jj;
    int row_l = rg * 16 + rl;
    size_t grow = arow0 + row_l; if (grow > 8191) grow = 8191;
    int g = gl ^ ((row_l >> 1) & 3);
    dma16(xc + grow * DIN + g * 8, As + rg * 512);
  }
#pragma unroll
  for (int jj = 0; jj < 2; ++jj) {
    int cg = w * 2 + jj;
    int col_l = cg * 16 + rl;
    dma16(W1p + ((size_t)(k * 32) * 512 + slice * 128 + col_l) * 32 + gl * 8,
          Bs + cg * 512);
  }

  const f32x4 zero4 = {0.f, 0.f, 0.f, 0.f};
  f32x4 acc[4][4];
#pragma unroll
  for (int fr = 0; fr < 4; ++fr)
#pragma unroll
    for (int fc = 0; fc < 4; ++fc) acc[fr][fc] = zero4;

  for (int t = 0; t < 32; ++t) {
    const int buf = t & 1;
    if (t < 31) {
      const int tn = t + 1, bn = buf ^ 1;
#pragma unroll
      for (int jj = 0; jj < 2; ++jj) {
        int rg = w * 2 + jj;
        int row_l = rg * 16 + rl;
        size_t grow = arow0 + row_l; if (grow > 8191) grow = 8191;
        int g = gl ^ ((row_l >> 1) & 3);
        dma16(xc + grow * DIN + tn * 32 + g * 8, As + bn * 4096 + rg * 512);
      }
#pragma unroll
      for (int jj = 0; jj < 2; ++jj) {
        int cg = w * 2 + jj;
        int col_l = cg * 16 + rl;
        dma16(W1p + ((size_t)(k * 32 + tn) * 512 + slice * 128 + col_l) * 32 +
                  gl * 8,
              Bs + bn * 4096 + cg * 512);
      }
      asm volatile("s_waitcnt vmcnt(4)" ::: "memory");
    } else {
      asm volatile("s_waitcnt vmcnt(0)" ::: "memory");
    }
    __syncthreads();
    bf16x8 af[4], bfr[4];
#pragma unroll
    for (int fr = 0; fr < 4; ++fr) {
      int row = wr * 64 + fr * 16 + l16;
      af[fr] = *(const bf16x8*)&As[buf * 4096 + row * 32 +
                                   ((quad ^ ((row >> 1) & 3)) << 3)];
    }
#pragma unroll
    for (int fc = 0; fc < 4; ++fc) {
      int col = wc * 64 + fc * 16 + l16;
      bfr[fc] = *(const bf16x8*)&Bs[buf * 4096 + col * 32 +
                                    ((quad ^ ((col >> 1) & 3)) << 3)];
    }
#pragma unroll
    for (int fr = 0; fr < 4; ++fr)
#pragma unroll
      for (int fc = 0; fc < 4; ++fc)
        acc[fr][fc] = __builtin_amdgcn_mfma_f32_16x16x32_bf16(
            af[fr], bfr[fc], acc[fr][fc], 0, 0, 0);
    __syncthreads();
  }

  // epilogue: bias+relu -> bf16 via LDS [128][136] -> h1 (b128 stores)
#pragma unroll
  for (int fr = 0; fr < 4; ++fr)
#pragma unroll
    for (int fc = 0; fc < 4; ++fc) {
      int col = wc * 64 + fc * 16 + l16;
      float bias = b1[k * DH + slice * 128 + col];
#pragma unroll
      for (int r = 0; r < 4; ++r) {
        int row = wr * 64 + fr * 16 + quad * 4 + r;
        lds[row * 136 + col] = f2bf(fmaxf(acc[fr][fc][r] + bias, 0.f));
      }
    }
  __syncthreads();
  {
    int row = tid >> 1, half = tid & 1;
    if (row0 + row < cntk) {
      u16* dst = h1 + (arow0 + row) * DH + slice * 128 + half * 64;
      const u16* srcl = &lds[row * 136 + half * 64];
#pragma unroll
      for (int j = 0; j < 8; ++j)
        *(bf16x8*)(dst + j * 8) = *(const bf16x8*)(srcl + j * 8);
    }
  }
}

// phi2: same structure, K=512 (16 K-tiles), A = compact h1, epilogue =
// masked mean-pool numerator -> psum atomics.
__global__ __launch_bounds__(256, 2) void phi2_kernel(
    const u16* __restrict__ h1, const u16* __restrict__ W2p,
    const float* __restrict__ b2, const int* __restrict__ cnt,
    float* __restrict__ psum) {
  const int slice = blockIdx.x, k = blockIdx.y, chunk = blockIdx.z;
  const int cntk = cnt[k];
  const int row0 = chunk * 128;
  if (row0 >= cntk) return;
  int cbase = 0;
#pragma unroll
  for (int i = 0; i < KC - 1; ++i) cbase += (i < k) ? cnt[i] : 0;

  const int tid = threadIdx.x;
  const int w = tid >> 6, lane = tid & 63;
  const int quad = lane >> 4, l16 = lane & 15;
  const int wr = w >> 1, wc = w & 1;
  const int rl = lane >> 2, gl = lane & 3;

  __shared__ __align__(16) u16 lds[16384];
  u16* As = lds;
  u16* Bs = lds + 8192;

  const size_t arow0 = (size_t)(cbase + row0);

#pragma unroll
  for (int jj = 0; jj < 2; ++jj) {
    int rg = w * 2 + jj;
    int row_l = rg * 16 + rl;
    size_t grow = arow0 + row_l; if (grow > 8191) grow = 8191;
    int g = gl ^ ((row_l >> 1) & 3);
    dma16(h1 + grow * DH + g * 8, As + rg * 512);
  }
#pragma unroll
  for (int jj = 0; jj < 2; ++jj) {
    int cg = w * 2 + jj;
    int col_l = cg * 16 + rl;
    dma16(W2p + ((size_t)(k * 16) * 512 + slice * 128 + col_l) * 32 + gl * 8,
          Bs + cg * 512);
  }

  const f32x4 zero4 = {0.f, 0.f, 0.f, 0.f};
  f32x4 acc[4][4];
#pragma unroll
  for (int fr = 0; fr < 4; ++fr)
#pragma unroll
    for (int fc = 0; fc < 4; ++fc) acc[fr][fc] = zero4;

  for (int t = 0; t < 16; ++t) {
    const int buf = t & 1;
    if (t < 15) {
      const int tn = t + 1, bn = buf ^ 1;
#pragma unroll
      for (int jj = 0; jj < 2; ++jj) {
        int rg = w * 2 + jj;
        int row_l = rg * 16 + rl;
        size_t grow = arow0 + row_l; if (grow > 8191) grow = 8191;
        int g = gl ^ ((row_l >> 1) & 3);
        dma16(h1 + grow * DH + tn * 32 + g * 8, As + bn * 4096 + rg * 512);
      }
#pragma unroll
      for (int jj = 0; jj < 2; ++jj) {
        int cg = w * 2 + jj;
        int col_l = cg * 16 + rl;
        dma16(W2p + ((size_t)(k * 16 + tn) * 512 + slice * 128 + col_l) * 32 +
                  gl * 8,
              Bs + bn * 4096 + cg * 512);
      }
      asm volatile("s_waitcnt vmcnt(4)" ::: "memory");
    } else {
      asm volatile("s_waitcnt vmcnt(0)" ::: "memory");
    }
    __syncthreads();
    bf16x8 af[4], bfr[4];
#pragma unroll
    for (int fr = 0; fr < 4; ++fr) {
      int row = wr * 64 + fr * 16 + l16;
      af[fr] = *(const bf16x8*)&As[buf * 4096 + row * 32 +
                                   ((quad ^ ((row >> 1) & 3)) << 3)];
    }
#pragma unroll
    for (int fc = 0; fc < 4; ++fc) {
      int col = wc * 64 + fc * 16 + l16;
      bfr[fc] = *(const bf16x8*)&Bs[buf * 4096 + col * 32 +
                                    ((quad ^ ((col >> 1) & 3)) << 3)];
    }
#pragma unroll
    for (int fr = 0; fr < 4; ++fr)
#pragma unroll
      for (int fc = 0; fc < 4; ++fc)
        acc[fr][fc] = __builtin_amdgcn_mfma_f32_16x16x32_bf16(
            af[fr], bfr[fc], acc[fr][fc], 0, 0, 0);
    __syncthreads();
  }

  // masked mean-pool numerator -> psum atomics
#pragma unroll
  for (int fc = 0; fc < 4; ++fc) {
    int col = wc * 64 + fc * 16 + l16;
    float bias = b2[k * DH + slice * 128 + col];
    float sv = 0.f;
#pragma unroll
    for (int fr = 0; fr < 4; ++fr)
#pragma unroll
      for (int r = 0; r < 4; ++r) {
        int row = row0 + wr * 64 + fr * 16 + quad * 4 + r;
        sv += (row < cntk) ? fmaxf(acc[fr][fc][r] + bias, 0.f) : 0.f;
      }
    sv += __shfl_xor(sv, 16, 64);
    sv += __shfl_xor(sv, 32, 64);
    if (quad == 0) atomicAdd(&psum[k * DH + slice * 128 + col], sv);
  }
}

// ---------------------------------------------------------------------------
// Fused tail: fc + gated-attn + softmax + rho + classifier in ONE kernel.
// 64 blocks x 256 threads, device-scope spin barriers between stages.
#define NTB 64

__device__ __forceinline__ void bar_arrive_wait(int* bar) {
  __syncthreads();
  if (threadIdx.x == 0) {
    __threadfence();
    __hip_atomic_fetch_add(bar, 1, __ATOMIC_RELEASE, __HIP_MEMORY_SCOPE_AGENT);
    while (__hip_atomic_load(bar, __ATOMIC_ACQUIRE,
                             __HIP_MEMORY_SCOPE_AGENT) < NTB) {
      __builtin_amdgcn_s_sleep(1);
    }
  }
  __syncthreads();
}

__global__ __launch_bounds__(256) void tail_kernel(
    const float* __restrict__ psum, const int* __restrict__ cnt,
    const float* __restrict__ fcW, const float* __restrict__ fcb,
    const float* __restrict__ Va, const float* __restrict__ ba,
    const float* __restrict__ Vb, const float* __restrict__ bb_,
    const float* __restrict__ Vc, const float* __restrict__ rhoW,
    const float* __restrict__ rhob, const float* __restrict__ clsW,
    const float* __restrict__ clsb, float* __restrict__ hstore,
    float* __restrict__ sred, float* __restrict__ h2g,
    int* __restrict__ bar, float* __restrict__ out) {
  __shared__ float p_sh[KC * DH];      // 20 KB (pooled feats, then hstore)
  __shared__ float r1[2560];           // 10 KB
  __shared__ float r2[2560];           // 10 KB
  __shared__ float invs[KC];
  __shared__ float gate_sh[4 * KC];
  __shared__ float ws_sh[KC];
  __shared__ float hp_sh[DH];
  const int tid = threadIdx.x;
  const int b = blockIdx.x;

  // ---- stage 1: fc — hstore[k][j] for j in [b*8, b*8+8)
  if (tid < KC) {
    int c = cnt[tid];
    invs[tid] = (c > 0) ? 1.f / (float)c : 0.f;
  }
  __syncthreads();
#pragma unroll
  for (int it = 0; it < KC * DH / 256; ++it) {
    int e = it * 256 + tid;
    p_sh[e] = psum[e] * invs[e >> 9];
  }
  __syncthreads();
  {
    const int jj = tid & 7, dq = tid >> 3;   // 8 j x 32 d-chunks of 16
    const int j0 = b * 8;
    float acc[KC];
#pragma unroll
    for (int k = 0; k < KC; ++k) acc[k] = 0.f;
#pragma unroll 4
    for (int i = 0; i < 16; ++i) {
      int d = dq * 16 + i;
      float wv = fcW[(size_t)d * DH + j0 + jj];
#pragma unroll
      for (int k = 0; k < KC; ++k) acc[k] = fmaf(p_sh[k * DH + d], wv, acc[k]);
    }
#pragma unroll
    for (int k = 0; k < KC; ++k) r1[(dq * 8 + jj) * KC + k] = acc[k];
    __syncthreads();
    if (tid < 8 * KC) {
      int jj2 = tid / KC, k = tid % KC;
      float s = 0.f;
#pragma unroll
      for (int q = 0; q < 32; ++q) s += r1[(q * 8 + jj2) * KC + k];
      hstore[k * DH + j0 + jj2] = fmaxf(s + fcb[j0 + jj2], 0.f);
    }
  }
  bar_arrive_wait(&bar[0]);

  // ---- stage 2: gated attention partials — 4 j per block
#pragma unroll
  for (int it = 0; it < KC * DH / 256; ++it) {
    int e = it * 256 + tid;
    p_sh[e] = hstore[e];
  }
  __syncthreads();
  {
    const int jj = tid & 3, dq = tid >> 2;   // 4 j x 64 d-chunks of 8
    const int j0 = b * 4;
    float sa[KC], sb[KC];
#pragma unroll
    for (int k = 0; k < KC; ++k) { sa[k] = 0.f; sb[k] = 0.f; }
#pragma unroll 4
    for (int i = 0; i < 8; ++i) {
      int d = dq * 8 + i;
      float va = Va[(size_t)d * DA + j0 + jj];
      float vb = Vb[(size_t)d * DA + j0 + jj];
#pragma unroll
      for (int k = 0; k < KC; ++k) {
        float h = p_sh[k * DH + d];
        sa[k] = fmaf(h, va, sa[k]);
        sb[k] = fmaf(h, vb, sb[k]);
      }
    }
#pragma unroll
    for (int k = 0; k < KC; ++k) {
      r1[(dq * 4 + jj) * KC + k] = sa[k];
      r2[(dq * 4 + jj) * KC + k] = sb[k];
    }
    __syncthreads();
    if (tid < 4 * KC) {
      int jj2 = tid / KC, k = tid % KC;
      float ta = 0.f, tb = 0.f;
#pragma unroll
      for (int q = 0; q < 64; ++q) {
        ta += r1[(q * 4 + jj2) * KC + k];
        tb += r2[(q * 4 + jj2) * KC + k];
      }
      float a = tanhf(ta + ba[j0 + jj2]);
      float g = 1.f / (1.f + expf(-(tb + bb_[j0 + jj2])));
      gate_sh[jj2 * KC + k] = a * g * Vc[j0 + jj2];  // bc dropped: shift-inv
    }
    __syncthreads();
    if (tid < KC) {
      float s = 0.f;
#pragma unroll
      for (int jj2 = 0; jj2 < 4; ++jj2) s += gate_sh[jj2 * KC + tid];
      sred[b * 16 + tid] = s;
    }
  }
  bar_arrive_wait(&bar[1]);

  // ---- stage 3: softmax over clusters + h_path + rho (4 j per block)
  if (tid < KC) {
    float s = 0.f;
    for (int q = 0; q < NTB; ++q) s += sred[q * 16 + tid];
    ws_sh[tid] = s;
  }
  __syncthreads();
  if (tid == 0) {
    float m = -1e30f;
#pragma unroll
    for (int k2 = 0; k2 < KC; ++k2) m = fmaxf(m, ws_sh[k2]);
    float Z = 0.f;
#pragma unroll
    for (int k2 = 0; k2 < KC; ++k2) {
      float e = expf(ws_sh[k2] - m);
      ws_sh[k2] = e;
      Z += e;
    }
    float iZ = 1.f / Z;
#pragma unroll
    for (int k2 = 0; k2 < KC; ++k2) ws_sh[k2] *= iZ;
  }
  __syncthreads();
#pragma unroll
  for (int it = 0; it < 2; ++it) {
    int d = it * 256 + tid;
    float s = 0.f;
#pragma unroll
    for (int k2 = 0; k2 < KC; ++k2) s = fmaf(ws_sh[k2], p_sh[k2 * DH + d], s);
    hp_sh[d] = s;
  }
  __syncthreads();
  {
    const int jj = tid & 3, dq = tid >> 2;
    const int j0 = b * 4;
    float acc = 0.f;
#pragma unroll 4
    for (int i = 0; i < 8; ++i) {
      int d = dq * 8 + i;
      acc = fmaf(hp_sh[d], rhoW[(size_t)d * DA + j0 + jj], acc);
    }
    r1[dq * 4 + jj] = acc;
    __syncthreads();
    if (tid < 4) {
      float s = 0.f;
#pragma unroll
      for (int q = 0; q < 64; ++q) s += r1[q * 4 + tid];
      h2g[j0 + tid] = fmaxf(s + rhob[j0 + tid], 0.f);
    }
  }

  // ---- stage 4: classifier (block 0 only; others arrive and exit)
  if (b != 0) {
    __syncthreads();
    if (tid == 0) {
      __threadfence();
      __hip_atomic_fetch_add(&bar[2], 1, __ATOMIC_RELEASE,
                             __HIP_MEMORY_SCOPE_AGENT);
    }
    return;
  }
  bar_arrive_wait(&bar[2]);
  {
    float h = h2g[tid];
#pragma unroll
    for (int c = 0; c < NCLS; ++c)
      r1[c * 256 + tid] = h * clsW[(size_t)tid * NCLS + c];
    __syncthreads();
    for (int s = 128; s > 0; s >>= 1) {
      if (tid < s) {
#pragma unroll
        for (int c = 0; c < NCLS; ++c)
          r1[c * 256 + tid] += r1[c * 256 + tid + s];
      }
      __syncthreads();
    }
    if (tid == 0) {
      float lg[NCLS], hz[NCLS];
      int best = 0;
#pragma unroll
      for (int c = 0; c < NCLS; ++c) {
        lg[c] = r1[c * 256] + clsb[c];
        hz[c] = 1.f / (1.f + expf(-lg[c]));
        if (lg[c] > lg[best]) best = c;
      }
      float S = 1.f;
#pragma unroll
      for (int c = 0; c < NCLS; ++c) out[c] = hz[c];
#pragma unroll
      for (int c = 0; c < NCLS; ++c) {
        S *= (1.f - hz[c]);
        out[NCLS + c] = S;
      }
      out[2 * NCLS] = (float)best;
    }
  }
}

extern "C" void kernel_launch(void* const* d_in, const int* in_sizes, int n_in,
                              void* d_out, int out_size, void* d_ws,
                              size_t ws_size, hipStream_t stream) {
  const float* x    = (const float*)d_in[0];
  const int*   cid  = (const int*)d_in[1];
  const float* W1   = (const float*)d_in[2];
  const float* b1   = (const float*)d_in[3];
  const float* W2   = (const float*)d_in[4];
  const float* b2   = (const float*)d_in[5];
  const float* fcW  = (const float*)d_in[6];
  const float* fcb  = (const float*)d_in[7];
  const float* Va   = (const float*)d_in[8];
  const float* ba   = (const float*)d_in[9];
  const float* Vb   = (const float*)d_in[10];
  const float* bb_  = (const float*)d_in[11];
  const float* Vc   = (const float*)d_in[12];
  const float* rhoW = (const float*)d_in[14];
  const float* rhob = (const float*)d_in[15];
  const float* clsW = (const float*)d_in[16];
  const float* clsb = (const float*)d_in[17];
  float* out = (float*)d_out;

  char* ws = (char*)d_ws;
  int*   cnt     = (int*)(ws + OFF_CNT);
  int*   bar     = (int*)(ws + OFF_BAR);
  int*   idxlist = (int*)(ws + OFF_IDX);
  float* psum    = (float*)(ws + OFF_PSUM);
  float* hstore  = (float*)(ws + OFF_H);
  float* h2g     = (float*)(ws + OFF_H2);
  float* sred    = (float*)(ws + OFF_SRED);
  u16*   W1p     = (u16*)(ws + OFF_W1P);
  u16*   W2p     = (u16*)(ws + OFF_W2P);
  u16*   xc      = (u16*)(ws + OFF_XC);
  u16*   h1      = (u16*)(ws + OFF_H1);

  (void)hipMemsetAsync(cnt, 0, 64, stream);  // cnt[10] + bar[3]
  prep_kernel<<<NB_PREP, 256, 0, stream>>>(cid, cnt, idxlist, W1, W2, W1p, W2p,
                                           psum);
  pack_kernel<<<NPATCH / 32, 256, 0, stream>>>(x, cnt, idxlist, xc);
  phi1_kernel<<<dim3(4, KC, 64), 256, 0, stream>>>(xc, W1p, b1, cnt, h1);
  phi2_kernel<<<dim3(4, KC, 64), 256, 0, stream>>>(h1, W2p, b2, cnt, psum);
  tail_kernel<<<NTB, 256, 0, stream>>>(psum, cnt, fcW, fcb, Va, ba, Vb, bb_,
                                       Vc, rhoW, rhob, clsW, clsb, hstore,
                                       sred, h2g, bar, out);
}